// Round 10
// baseline (622.665 us; speedup 1.0000x reference)
//
#include <hip/hip_runtime.h>
#include <hip/hip_bf16.h>

#define NN 50000
#define NE 800000
#define DD 512
#define NPAD 50048   // 391 * 128, for 128-row GEMM tiles
#define STRIDE 96    // bucket-CSR slot count; P(deg >= 96) ~ 1e-30 for Poisson(16)

typedef __attribute__((ext_vector_type(8))) short bf16x8;
typedef __attribute__((ext_vector_type(4))) float f32x4;
typedef __attribute__((ext_vector_type(8))) unsigned short u16x8;

// R10 = R6 EXACTLY (best, 403.2 us) + 4 idempotent dummy_fill probe launches.
// Books after R8/R9: gap/launch ~3 us, gemm ~51 us warm, agg 131.5, and
// prep + fixed-overhead ~ 210 us with prep <= 132 (top-5 cut). The only
// plausible expensive piece of prep is fill (800K device-scope atomics +
// 800K random 4B stores -> write-allocate + partial-line writebacks).
// Probe: dummy_fill x4 replicates fill's work against scratch arrays;
// fill_us ~= (total - 403.2 - 12)/4. Decides fill-rewrite vs harness-floor.
__device__ __align__(16) unsigned short g_Wt[DD * DD];            // W^T bf16
__device__ __align__(16) unsigned short g_xb[(size_t)NN * DD];    // x in bf16 (51 MB)
__device__ __align__(16) unsigned short g_agg[(size_t)NPAD * DD]; // bf16 agg (A matrix)
__device__ unsigned g_cnt[NN];                                    // static zero-init
__device__ int g_eidx[(size_t)NN * STRIDE];                       // bucket CSR
__device__ unsigned g_cnt2[NN];                                   // probe scratch
__device__ int g_eidx2[(size_t)NN * STRIDE];                      // probe scratch

// round-to-nearest-even fp32 -> bf16 (finite normal inputs)
static __device__ __forceinline__ unsigned short f2bf(float f) {
    unsigned u = __float_as_uint(f);
    u += 0x7fff + ((u >> 16) & 1);
    return (unsigned short)(u >> 16);
}
static __device__ __forceinline__ float bf2f(unsigned short u) {
    return __uint_as_float((unsigned)u << 16);
}

// Fused prep: fill (edge scatter) runs CONCURRENTLY with x->bf16 conv, W^T, pad-zero.
#define FB_FILL 3125                 // 800000 / 256 exactly
#define FB_CONV (FB_FILL + 12500)    // 50000*512/8/256
#define FB_WT   (FB_CONV + 1024)     // 512*512/256
#define FB_END  (FB_WT + 12)         // 48 pad rows * 512 / 8 / 256

__global__ void prep_all(const float* __restrict__ x, const float* __restrict__ W,
                         const int* __restrict__ src, const int* __restrict__ dst) {
    int b = blockIdx.x;
    int tid = threadIdx.x;
    if (b < FB_FILL) {
        int i = b * 256 + tid;                     // NE = 3125*256 exactly
        int d = dst[i];
        unsigned pos = atomicAdd(&g_cnt[d], 1u);
        if (pos < STRIDE) g_eidx[(size_t)d * STRIDE + pos] = src[i];
    } else if (b < FB_CONV) {
        size_t base = ((size_t)(b - FB_FILL) * 256 + tid) * 8;
        // x is read exactly once: nontemporal load, don't install 102 MB in L2
        f32x4 v0 = __builtin_nontemporal_load((const f32x4*)(x + base));
        f32x4 v1 = __builtin_nontemporal_load((const f32x4*)(x + base) + 1);
        u16x8 o;
        o[0] = f2bf(v0[0]); o[1] = f2bf(v0[1]); o[2] = f2bf(v0[2]); o[3] = f2bf(v0[3]);
        o[4] = f2bf(v1[0]); o[5] = f2bf(v1[1]); o[6] = f2bf(v1[2]); o[7] = f2bf(v1[3]);
        *(u16x8*)(g_xb + base) = o;                // normal store
    } else if (b < FB_WT) {
        int idx = (b - FB_CONV) * 256 + tid;       // coalesced read of W
        int k = idx >> 9, n = idx & 511;
        g_Wt[n * DD + k] = f2bf(W[idx]);           // g_Wt[n][k] = W[k][n]
    } else {
        int i = (b - FB_WT) * 256 + tid;           // 0..3071: zero 48 GEMM pad rows
        u16x8 z = {0, 0, 0, 0, 0, 0, 0, 0};
        *(u16x8*)(g_agg + (size_t)NN * DD + (size_t)i * 8) = z;
    }
}

// PROBE: replicates fill's exact work (2 coalesced loads, 1 device-scope
// atomicAdd, 1 scattered 4B store) against scratch arrays. pos&63 keeps the
// store unconditional and replay-stable (real fill's pos<96 guard passes ~100%
// of the time, so traffic matches). Idempotent w.r.t. the real pipeline.
__global__ void dummy_fill(const int* __restrict__ src, const int* __restrict__ dst) {
    int i = blockIdx.x * 256 + threadIdx.x;
    int d = dst[i];
    unsigned pos = atomicAdd(&g_cnt2[d], 1u);
    g_eidx2[(size_t)d * STRIDE + (pos & 63)] = src[i];
}

// one wave per node: gather bf16 rows, fp32 register accumulation, bf16 write.
// Structurally done: 418 MB random-line fetch @ ~3.3 TB/s fabric wall (R3 MLP
// A/B flat; R5 slicing regressed; R9 fusion regressed).
__global__ void aggregate() {
    int v = (blockIdx.x * blockDim.x + threadIdx.x) >> 6;
    int lane = threadIdx.x & 63;
    if (v >= NN) return;
    int deg = (int)g_cnt[v];
    if (deg > STRIDE) deg = STRIDE;
    const int* seg = g_eidx + (size_t)v * STRIDE;
    float a[8] = {0.f, 0.f, 0.f, 0.f, 0.f, 0.f, 0.f, 0.f};
    int i = 0;
    for (; i + 3 < deg; i += 4) {  // 4 KB in flight per wave
        int s0 = seg[i], s1 = seg[i + 1], s2 = seg[i + 2], s3 = seg[i + 3];
        int4 q0 = *((const int4*)(g_xb + ((size_t)s0 << 9)) + lane);
        int4 q1 = *((const int4*)(g_xb + ((size_t)s1 << 9)) + lane);
        int4 q2 = *((const int4*)(g_xb + ((size_t)s2 << 9)) + lane);
        int4 q3 = *((const int4*)(g_xb + ((size_t)s3 << 9)) + lane);
        const unsigned short* u0 = (const unsigned short*)&q0;
        const unsigned short* u1 = (const unsigned short*)&q1;
        const unsigned short* u2 = (const unsigned short*)&q2;
        const unsigned short* u3 = (const unsigned short*)&q3;
#pragma unroll
        for (int j = 0; j < 8; ++j)
            a[j] += (bf2f(u0[j]) + bf2f(u1[j])) + (bf2f(u2[j]) + bf2f(u3[j]));
    }
    for (; i + 1 < deg; i += 2) {
        int s0 = seg[i], s1 = seg[i + 1];
        int4 q0 = *((const int4*)(g_xb + ((size_t)s0 << 9)) + lane);
        int4 q1 = *((const int4*)(g_xb + ((size_t)s1 << 9)) + lane);
        const unsigned short* u0 = (const unsigned short*)&q0;
        const unsigned short* u1 = (const unsigned short*)&q1;
#pragma unroll
        for (int j = 0; j < 8; ++j) a[j] += bf2f(u0[j]) + bf2f(u1[j]);
    }
    if (i < deg) {
        int s0 = seg[i];
        int4 q0 = *((const int4*)(g_xb + ((size_t)s0 << 9)) + lane);
        const unsigned short* u0 = (const unsigned short*)&q0;
#pragma unroll
        for (int j = 0; j < 8; ++j) a[j] += bf2f(u0[j]);
    }
    u16x8 o;
#pragma unroll
    for (int j = 0; j < 8; ++j) o[j] = f2bf(a[j]);
    *(u16x8*)(g_agg + ((size_t)v << 9) + lane * 8) = o;
}

// GEMM: m97 fragment structure, 128x256 tile, BK=32, 8 waves (2x4), 4x4 frags/wave.
#define BM 128
#define BN 256
#define BK 32
#define NWG ((NPAD / BM) * (DD / BN))   // 391*2 = 782

__global__ __launch_bounds__(512) void gemm_kernel(float* __restrict__ out,
                                                   const float* __restrict__ bias) {
    __shared__ __align__(16) unsigned short As[BM * BK];   // 8 KB, [m][k] linear
    __shared__ __align__(16) unsigned short Bs[BN * BK];   // 16 KB, [n][k] linear

    // zero g_cnt for the NEXT graph replay (runs after aggregate's last read).
    {
        int gid = blockIdx.x * 512 + threadIdx.x;   // 782*512 >= NN
        if (gid < NN) g_cnt[gid] = 0;
    }

    // bijective XCD swizzle (m204 form; NWG = 782, r = 6)
    const int q = NWG >> 3, r = NWG & 7;
    int xcd = blockIdx.x & 7, sub = blockIdx.x >> 3;
    int swz = (xcd < r) ? xcd * (q + 1) + sub : r * (q + 1) + (xcd - r) * q + sub;
    const int m0 = (swz >> 1) * BM;
    const int n0 = (swz & 1) * BN;

    const int tid = threadIdx.x;
    const int wave = tid >> 6, lane = tid & 63;
    const int wm = wave >> 2, wn = wave & 3;       // 2x4 waves -> 64x64 quadrants
    const int quad = lane >> 4, l16 = lane & 15;

    const int srow = lane >> 2;          // staging: 0..15
    const int skoff = (lane & 3) * 8;    // shorts

    f32x4 acc[4][4];
#pragma unroll
    for (int i = 0; i < 4; ++i)
#pragma unroll
        for (int j = 0; j < 4; ++j) acc[i][j] = (f32x4){0.f, 0.f, 0.f, 0.f};

    const unsigned short* gA = g_agg + (size_t)m0 * DD;
    const unsigned short* gB = g_Wt + (size_t)n0 * DD;

    for (int k0 = 0; k0 < DD; k0 += BK) {
        // 24 chunks of 1 KB (A: 0..7, B: 8..23), 3 per wave; wave-uniform LDS
        // base, HW adds lane*16 -> linear [row][k].
#pragma unroll
        for (int i = 0; i < 3; ++i) {
            int c = wave * 3 + i;
            if (c < 8) {
                __builtin_amdgcn_global_load_lds(
                    (const __attribute__((address_space(1))) void*)
                        (gA + (size_t)(c * 16 + srow) * DD + k0 + skoff),
                    (__attribute__((address_space(3))) void*)(As + c * 512), 16, 0, 0);
            } else {
                __builtin_amdgcn_global_load_lds(
                    (const __attribute__((address_space(1))) void*)
                        (gB + (size_t)((c - 8) * 16 + srow) * DD + k0 + skoff),
                    (__attribute__((address_space(3))) void*)(Bs + (c - 8) * 512), 16, 0, 0);
            }
        }
        __syncthreads();   // compiler emits vmcnt(0) drain before s_barrier

        bf16x8 af[4], bf[4];
#pragma unroll
        for (int t = 0; t < 4; ++t) {
            af[t] = *(const bf16x8*)(&As[(wm * 64 + t * 16 + l16) * BK + quad * 8]);
            bf[t] = *(const bf16x8*)(&Bs[(wn * 64 + t * 16 + l16) * BK + quad * 8]);
        }
#pragma unroll
        for (int am = 0; am < 4; ++am)
#pragma unroll
            for (int bn = 0; bn < 4; ++bn)
                acc[am][bn] = __builtin_amdgcn_mfma_f32_16x16x32_bf16(
                    af[am], bf[bn], acc[am][bn], 0, 0, 0);
        __syncthreads();
    }

    // Epilogue: C/D layout col=l16, row=quad*4+r (m89/m91-verified).
#pragma unroll
    for (int am = 0; am < 4; ++am) {
        int row_base = m0 + wm * 64 + am * 16 + quad * 4;
#pragma unroll
        for (int bn = 0; bn < 4; ++bn) {
            int col = n0 + wn * 64 + bn * 16 + l16;
            float bv = bias[col];
#pragma unroll
            for (int rr = 0; rr < 4; ++rr) {
                int rowi = row_base + rr;
                if (rowi < NN) out[(size_t)rowi * DD + col] = acc[am][bn][rr] + bv;
            }
        }
    }
}

extern "C" void kernel_launch(void* const* d_in, const int* in_sizes, int n_in,
                              void* d_out, int out_size, void* d_ws, size_t ws_size,
                              hipStream_t stream) {
    const float* x    = (const float*)d_in[0];
    const float* W    = (const float*)d_in[1];
    const float* bias = (const float*)d_in[2];
    const int*   src  = (const int*)d_in[3];
    const int*   dst  = (const int*)d_in[4];
    float* out = (float*)d_out;
    (void)d_ws; (void)ws_size;

    prep_all<<<FB_END, 256, 0, stream>>>(x, W, src, dst);        // fill || conv || Wt
    aggregate<<<(NN * 64 + 255) / 256, 256, 0, stream>>>();      // one wave/node
    gemm_kernel<<<NWG, 512, 0, stream>>>(out, bias);             // 782 blocks
    // ---- probes (after the measured pipeline; scratch-only side effects) ----
    dummy_fill<<<FB_FILL, 256, 0, stream>>>(src, dst);
    dummy_fill<<<FB_FILL, 256, 0, stream>>>(src, dst);
    dummy_fill<<<FB_FILL, 256, 0, stream>>>(src, dst);
    dummy_fill<<<FB_FILL, 256, 0, stream>>>(src, dst);
}

// Round 11
// 475.987 us; speedup vs baseline: 1.3082x; 1.3082x over previous
//
#include <hip/hip_runtime.h>
#include <hip/hip_bf16.h>

#define NN 50000
#define NE 800000
#define DD 512
#define NPAD 50048   // 391 * 128, for 128-row GEMM tiles
#define STRIDE 96    // bucket-CSR slot count; P(deg >= 96) ~ 1e-30 for Poisson(16)

typedef __attribute__((ext_vector_type(8))) short bf16x8;
typedef __attribute__((ext_vector_type(4))) float f32x4;
typedef __attribute__((ext_vector_type(8))) unsigned short u16x8;

// R11 = R6 with ONE change: LDS-free direct-fragment GEMM.
// Books (R8/R10 probes): agg 131.5 (fabric wall) + gemm 54 + prep ~60 (fill 52
// measured) + gaps ~10 + ~140 harness-fixed (reset dispatches). gemm is 2x its
// ~27 us memory floor because LDS staging + vmcnt(0)+2 barriers/K-step expose
// latency for operands that are ALREADY L2-resident (B=512KB total; A=128KB
// panel, XCD-local, read 4x). Common-mistake #7: don't LDS-stage L2-fit data.
// Fix: per-lane bf16x8 fragment loads straight from global; zero barriers; the
// compiler pipelines loads across K-steps freely.
__device__ __align__(16) unsigned short g_Wt[DD * DD];            // W^T bf16
__device__ __align__(16) unsigned short g_xb[(size_t)NN * DD];    // x in bf16 (51 MB)
__device__ __align__(16) unsigned short g_agg[(size_t)NPAD * DD]; // bf16 agg (A matrix)
__device__ unsigned g_cnt[NN];                                    // static zero-init
__device__ int g_eidx[(size_t)NN * STRIDE];                       // bucket CSR

// round-to-nearest-even fp32 -> bf16 (finite normal inputs)
static __device__ __forceinline__ unsigned short f2bf(float f) {
    unsigned u = __float_as_uint(f);
    u += 0x7fff + ((u >> 16) & 1);
    return (unsigned short)(u >> 16);
}
static __device__ __forceinline__ float bf2f(unsigned short u) {
    return __uint_as_float((unsigned)u << 16);
}

// Fused prep: fill (edge scatter) runs CONCURRENTLY with x->bf16 conv, W^T, pad-zero.
#define FB_FILL 3125                 // 800000 / 256 exactly
#define FB_CONV (FB_FILL + 12500)    // 50000*512/8/256
#define FB_WT   (FB_CONV + 1024)     // 512*512/256
#define FB_END  (FB_WT + 12)         // 48 pad rows * 512 / 8 / 256

__global__ void prep_all(const float* __restrict__ x, const float* __restrict__ W,
                         const int* __restrict__ src, const int* __restrict__ dst) {
    int b = blockIdx.x;
    int tid = threadIdx.x;
    if (b < FB_FILL) {
        int i = b * 256 + tid;                     // NE = 3125*256 exactly
        int d = dst[i];
        unsigned pos = atomicAdd(&g_cnt[d], 1u);
        if (pos < STRIDE) g_eidx[(size_t)d * STRIDE + pos] = src[i];
    } else if (b < FB_CONV) {
        size_t base = ((size_t)(b - FB_FILL) * 256 + tid) * 8;
        // x is read exactly once: nontemporal load, don't install 102 MB in L2
        f32x4 v0 = __builtin_nontemporal_load((const f32x4*)(x + base));
        f32x4 v1 = __builtin_nontemporal_load((const f32x4*)(x + base) + 1);
        u16x8 o;
        o[0] = f2bf(v0[0]); o[1] = f2bf(v0[1]); o[2] = f2bf(v0[2]); o[3] = f2bf(v0[3]);
        o[4] = f2bf(v1[0]); o[5] = f2bf(v1[1]); o[6] = f2bf(v1[2]); o[7] = f2bf(v1[3]);
        *(u16x8*)(g_xb + base) = o;                // normal store
    } else if (b < FB_WT) {
        int idx = (b - FB_CONV) * 256 + tid;       // coalesced read of W
        int k = idx >> 9, n = idx & 511;
        g_Wt[n * DD + k] = f2bf(W[idx]);           // g_Wt[n][k] = W[k][n]
    } else {
        int i = (b - FB_WT) * 256 + tid;           // 0..3071: zero 48 GEMM pad rows
        u16x8 z = {0, 0, 0, 0, 0, 0, 0, 0};
        *(u16x8*)(g_agg + (size_t)NN * DD + (size_t)i * 8) = z;
    }
}

// one wave per node: gather bf16 rows, fp32 register accumulation, bf16 write.
// Structurally done: 418 MB random-line fetch @ ~3.3 TB/s fabric wall (R3 MLP
// A/B flat; R5 slicing regressed; R9 fusion regressed).
__global__ void aggregate() {
    int v = (blockIdx.x * blockDim.x + threadIdx.x) >> 6;
    int lane = threadIdx.x & 63;
    if (v >= NN) return;
    int deg = (int)g_cnt[v];
    if (deg > STRIDE) deg = STRIDE;
    const int* seg = g_eidx + (size_t)v * STRIDE;
    float a[8] = {0.f, 0.f, 0.f, 0.f, 0.f, 0.f, 0.f, 0.f};
    int i = 0;
    for (; i + 3 < deg; i += 4) {  // 4 KB in flight per wave
        int s0 = seg[i], s1 = seg[i + 1], s2 = seg[i + 2], s3 = seg[i + 3];
        int4 q0 = *((const int4*)(g_xb + ((size_t)s0 << 9)) + lane);
        int4 q1 = *((const int4*)(g_xb + ((size_t)s1 << 9)) + lane);
        int4 q2 = *((const int4*)(g_xb + ((size_t)s2 << 9)) + lane);
        int4 q3 = *((const int4*)(g_xb + ((size_t)s3 << 9)) + lane);
        const unsigned short* u0 = (const unsigned short*)&q0;
        const unsigned short* u1 = (const unsigned short*)&q1;
        const unsigned short* u2 = (const unsigned short*)&q2;
        const unsigned short* u3 = (const unsigned short*)&q3;
#pragma unroll
        for (int j = 0; j < 8; ++j)
            a[j] += (bf2f(u0[j]) + bf2f(u1[j])) + (bf2f(u2[j]) + bf2f(u3[j]));
    }
    for (; i + 1 < deg; i += 2) {
        int s0 = seg[i], s1 = seg[i + 1];
        int4 q0 = *((const int4*)(g_xb + ((size_t)s0 << 9)) + lane);
        int4 q1 = *((const int4*)(g_xb + ((size_t)s1 << 9)) + lane);
        const unsigned short* u0 = (const unsigned short*)&q0;
        const unsigned short* u1 = (const unsigned short*)&q1;
#pragma unroll
        for (int j = 0; j < 8; ++j) a[j] += bf2f(u0[j]) + bf2f(u1[j]);
    }
    if (i < deg) {
        int s0 = seg[i];
        int4 q0 = *((const int4*)(g_xb + ((size_t)s0 << 9)) + lane);
        const unsigned short* u0 = (const unsigned short*)&q0;
#pragma unroll
        for (int j = 0; j < 8; ++j) a[j] += bf2f(u0[j]);
    }
    u16x8 o;
#pragma unroll
    for (int j = 0; j < 8; ++j) o[j] = f2bf(a[j]);
    *(u16x8*)(g_agg + ((size_t)v << 9) + lane * 8) = o;
}

// LDS-free GEMM: 128x256 tile, 8 waves (2x4), 4x4 16x16x32 frags/wave.
// Fragments load straight from global (16 B/lane); A-frag addresses identical
// across the 4 wn-waves (L1 hits), B-frags across wm-pairs; B = 512 KB Wt is
// L2-resident chip-wide. Zero barriers -> compiler pipelines K-steps freely.
#define BM 128
#define BN 256
#define NWG ((NPAD / BM) * (DD / BN))   // 391*2 = 782

__global__ __launch_bounds__(512) void gemm_kernel(float* __restrict__ out,
                                                   const float* __restrict__ bias) {
    // zero g_cnt for the NEXT graph replay (runs after aggregate's last read).
    {
        int gid = blockIdx.x * 512 + threadIdx.x;   // 782*512 >= NN
        if (gid < NN) g_cnt[gid] = 0;
    }

    // bijective XCD swizzle (m204 form; NWG = 782, r = 6): A-panel's 2 col-block
    // siblings land on one XCD L2.
    const int q = NWG >> 3, r = NWG & 7;
    int xcd = blockIdx.x & 7, sub = blockIdx.x >> 3;
    int swz = (xcd < r) ? xcd * (q + 1) + sub : r * (q + 1) + (xcd - r) * q + sub;
    const int m0 = (swz >> 1) * BM;
    const int n0 = (swz & 1) * BN;

    const int tid = threadIdx.x;
    const int wave = tid >> 6, lane = tid & 63;
    const int wm = wave >> 2, wn = wave & 3;       // 2x4 waves -> 64x64 quadrants
    const int quad = lane >> 4, l16 = lane & 15;

    f32x4 acc[4][4];
#pragma unroll
    for (int i = 0; i < 4; ++i)
#pragma unroll
        for (int j = 0; j < 4; ++j) acc[i][j] = (f32x4){0.f, 0.f, 0.f, 0.f};

    // per-lane fragment base pointers (row l16 of each 16-row frag strip)
    const unsigned short* pA =
        g_agg + (size_t)(m0 + wm * 64 + l16) * DD + quad * 8;
    const unsigned short* pB =
        g_Wt + (size_t)(n0 + wn * 64 + l16) * DD + quad * 8;

    for (int k0 = 0; k0 < DD; k0 += 32) {
        bf16x8 af[4], bf[4];
#pragma unroll
        for (int t = 0; t < 4; ++t) {
            af[t] = *(const bf16x8*)(pA + (size_t)t * 16 * DD + k0);
            bf[t] = *(const bf16x8*)(pB + (size_t)t * 16 * DD + k0);
        }
#pragma unroll
        for (int am = 0; am < 4; ++am)
#pragma unroll
            for (int bn = 0; bn < 4; ++bn)
                acc[am][bn] = __builtin_amdgcn_mfma_f32_16x16x32_bf16(
                    af[am], bf[bn], acc[am][bn], 0, 0, 0);
    }

    // Epilogue: C/D layout col=l16, row=quad*4+r (m89/m91-verified).
#pragma unroll
    for (int am = 0; am < 4; ++am) {
        int row_base = m0 + wm * 64 + am * 16 + quad * 4;
#pragma unroll
        for (int bn = 0; bn < 4; ++bn) {
            int col = n0 + wn * 64 + bn * 16 + l16;
            float bv = bias[col];
#pragma unroll
            for (int rr = 0; rr < 4; ++rr) {
                int rowi = row_base + rr;
                if (rowi < NN) out[(size_t)rowi * DD + col] = acc[am][bn][rr] + bv;
            }
        }
    }
}

extern "C" void kernel_launch(void* const* d_in, const int* in_sizes, int n_in,
                              void* d_out, int out_size, void* d_ws, size_t ws_size,
                              hipStream_t stream) {
    const float* x    = (const float*)d_in[0];
    const float* W    = (const float*)d_in[1];
    const float* bias = (const float*)d_in[2];
    const int*   src  = (const int*)d_in[3];
    const int*   dst  = (const int*)d_in[4];
    float* out = (float*)d_out;
    (void)d_ws; (void)ws_size;

    prep_all<<<FB_END, 256, 0, stream>>>(x, W, src, dst);        // fill || conv || Wt
    aggregate<<<(NN * 64 + 255) / 256, 256, 0, stream>>>();      // one wave/node
    gemm_kernel<<<NWG, 512, 0, stream>>>(out, bias);             // 782 blocks, no LDS
}

// Round 12
// 410.304 us; speedup vs baseline: 1.5176x; 1.1601x over previous
//
#include <hip/hip_runtime.h>
#include <hip/hip_bf16.h>

#define NN 50000
#define NE 800000
#define DD 512
#define NPAD 50048   // 391 * 128, for 128-row GEMM tiles
#define STRIDE 96    // bucket-CSR slot count; P(deg >= 96) ~ 1e-30 for Poisson(16)

typedef __attribute__((ext_vector_type(8))) short bf16x8;
typedef __attribute__((ext_vector_type(4))) float f32x4;
typedef __attribute__((ext_vector_type(8))) unsigned short u16x8;

// R12 = R6 (best, 403.2) + ONE change: nontemporal stores on the gemm's dense
// fp32 out epilogue (102 MB, write-once, fully coalesced full lines) so it
// doesn't evict A-panels/Wt from the 4MB XCD L2s mid-kernel. R1's NT regression
// was on SCATTERED 4B stores (write-allocate RMW + cold consumer) — different
// mechanism; dense-out NT was never isolated.
// Session books (measured): agg 131.5 = fabric wall (R3 MLP flat, R5 slice
// regressed, R9 fusion regressed); gemm 54 staged (137 LDS-free R11, 60 dbuf
// R3); fill ~52 (R10 probe); ~3 us/launch gap (R8 vs R10); ~140 us fixed
// harness dispatches in the timed region.
__device__ __align__(16) unsigned short g_Wt[DD * DD];            // W^T bf16
__device__ __align__(16) unsigned short g_xb[(size_t)NN * DD];    // x in bf16 (51 MB)
__device__ __align__(16) unsigned short g_agg[(size_t)NPAD * DD]; // bf16 agg (A matrix)
__device__ unsigned g_cnt[NN];                                    // static zero-init
__device__ int g_eidx[(size_t)NN * STRIDE];                       // bucket CSR

// round-to-nearest-even fp32 -> bf16 (finite normal inputs)
static __device__ __forceinline__ unsigned short f2bf(float f) {
    unsigned u = __float_as_uint(f);
    u += 0x7fff + ((u >> 16) & 1);
    return (unsigned short)(u >> 16);
}
static __device__ __forceinline__ float bf2f(unsigned short u) {
    return __uint_as_float((unsigned)u << 16);
}

// Fused prep: fill (edge scatter) runs CONCURRENTLY with x->bf16 conv, W^T, pad-zero.
#define FB_FILL 3125                 // 800000 / 256 exactly
#define FB_CONV (FB_FILL + 12500)    // 50000*512/8/256
#define FB_WT   (FB_CONV + 1024)     // 512*512/256
#define FB_END  (FB_WT + 12)         // 48 pad rows * 512 / 8 / 256

__global__ void prep_all(const float* __restrict__ x, const float* __restrict__ W,
                         const int* __restrict__ src, const int* __restrict__ dst) {
    int b = blockIdx.x;
    int tid = threadIdx.x;
    if (b < FB_FILL) {
        int i = b * 256 + tid;                     // NE = 3125*256 exactly
        int d = dst[i];
        unsigned pos = atomicAdd(&g_cnt[d], 1u);
        if (pos < STRIDE) g_eidx[(size_t)d * STRIDE + pos] = src[i];
    } else if (b < FB_CONV) {
        size_t base = ((size_t)(b - FB_FILL) * 256 + tid) * 8;
        // x is read exactly once: nontemporal load, don't install 102 MB in L2
        f32x4 v0 = __builtin_nontemporal_load((const f32x4*)(x + base));
        f32x4 v1 = __builtin_nontemporal_load((const f32x4*)(x + base) + 1);
        u16x8 o;
        o[0] = f2bf(v0[0]); o[1] = f2bf(v0[1]); o[2] = f2bf(v0[2]); o[3] = f2bf(v0[3]);
        o[4] = f2bf(v1[0]); o[5] = f2bf(v1[1]); o[6] = f2bf(v1[2]); o[7] = f2bf(v1[3]);
        *(u16x8*)(g_xb + base) = o;                // normal store
    } else if (b < FB_WT) {
        int idx = (b - FB_CONV) * 256 + tid;       // coalesced read of W
        int k = idx >> 9, n = idx & 511;
        g_Wt[n * DD + k] = f2bf(W[idx]);           // g_Wt[n][k] = W[k][n]
    } else {
        int i = (b - FB_WT) * 256 + tid;           // 0..3071: zero 48 GEMM pad rows
        u16x8 z = {0, 0, 0, 0, 0, 0, 0, 0};
        *(u16x8*)(g_agg + (size_t)NN * DD + (size_t)i * 8) = z;
    }
}

// one wave per node: gather bf16 rows, fp32 register accumulation, bf16 write.
// Structurally done: 418 MB random-line fetch @ ~3.3 TB/s fabric wall.
__global__ void aggregate() {
    int v = (blockIdx.x * blockDim.x + threadIdx.x) >> 6;
    int lane = threadIdx.x & 63;
    if (v >= NN) return;
    int deg = (int)g_cnt[v];
    if (deg > STRIDE) deg = STRIDE;
    const int* seg = g_eidx + (size_t)v * STRIDE;
    float a[8] = {0.f, 0.f, 0.f, 0.f, 0.f, 0.f, 0.f, 0.f};
    int i = 0;
    for (; i + 3 < deg; i += 4) {  // 4 KB in flight per wave
        int s0 = seg[i], s1 = seg[i + 1], s2 = seg[i + 2], s3 = seg[i + 3];
        int4 q0 = *((const int4*)(g_xb + ((size_t)s0 << 9)) + lane);
        int4 q1 = *((const int4*)(g_xb + ((size_t)s1 << 9)) + lane);
        int4 q2 = *((const int4*)(g_xb + ((size_t)s2 << 9)) + lane);
        int4 q3 = *((const int4*)(g_xb + ((size_t)s3 << 9)) + lane);
        const unsigned short* u0 = (const unsigned short*)&q0;
        const unsigned short* u1 = (const unsigned short*)&q1;
        const unsigned short* u2 = (const unsigned short*)&q2;
        const unsigned short* u3 = (const unsigned short*)&q3;
#pragma unroll
        for (int j = 0; j < 8; ++j)
            a[j] += (bf2f(u0[j]) + bf2f(u1[j])) + (bf2f(u2[j]) + bf2f(u3[j]));
    }
    for (; i + 1 < deg; i += 2) {
        int s0 = seg[i], s1 = seg[i + 1];
        int4 q0 = *((const int4*)(g_xb + ((size_t)s0 << 9)) + lane);
        int4 q1 = *((const int4*)(g_xb + ((size_t)s1 << 9)) + lane);
        const unsigned short* u0 = (const unsigned short*)&q0;
        const unsigned short* u1 = (const unsigned short*)&q1;
#pragma unroll
        for (int j = 0; j < 8; ++j) a[j] += bf2f(u0[j]) + bf2f(u1[j]);
    }
    if (i < deg) {
        int s0 = seg[i];
        int4 q0 = *((const int4*)(g_xb + ((size_t)s0 << 9)) + lane);
        const unsigned short* u0 = (const unsigned short*)&q0;
#pragma unroll
        for (int j = 0; j < 8; ++j) a[j] += bf2f(u0[j]);
    }
    u16x8 o;
#pragma unroll
    for (int j = 0; j < 8; ++j) o[j] = f2bf(a[j]);
    *(u16x8*)(g_agg + ((size_t)v << 9) + lane * 8) = o;
}

// GEMM: m97 fragment structure, 128x256 tile, BK=32, 8 waves (2x4), 4x4 frags/wave.
// LDS staging is load-bearing (R11: LDS-free = 137 us, latency-bound at 30% occ).
#define BM 128
#define BN 256
#define BK 32
#define NWG ((NPAD / BM) * (DD / BN))   // 391*2 = 782

__global__ __launch_bounds__(512) void gemm_kernel(float* __restrict__ out,
                                                   const float* __restrict__ bias) {
    __shared__ __align__(16) unsigned short As[BM * BK];   // 8 KB, [m][k] linear
    __shared__ __align__(16) unsigned short Bs[BN * BK];   // 16 KB, [n][k] linear

    // zero g_cnt for the NEXT graph replay (runs after aggregate's last read).
    {
        int gid = blockIdx.x * 512 + threadIdx.x;   // 782*512 >= NN
        if (gid < NN) g_cnt[gid] = 0;
    }

    // bijective XCD swizzle (m204 form; NWG = 782, r = 6)
    const int q = NWG >> 3, r = NWG & 7;
    int xcd = blockIdx.x & 7, sub = blockIdx.x >> 3;
    int swz = (xcd < r) ? xcd * (q + 1) + sub : r * (q + 1) + (xcd - r) * q + sub;
    const int m0 = (swz >> 1) * BM;
    const int n0 = (swz & 1) * BN;

    const int tid = threadIdx.x;
    const int wave = tid >> 6, lane = tid & 63;
    const int wm = wave >> 2, wn = wave & 3;       // 2x4 waves -> 64x64 quadrants
    const int quad = lane >> 4, l16 = lane & 15;

    const int srow = lane >> 2;          // staging: 0..15
    const int skoff = (lane & 3) * 8;    // shorts

    f32x4 acc[4][4];
#pragma unroll
    for (int i = 0; i < 4; ++i)
#pragma unroll
        for (int j = 0; j < 4; ++j) acc[i][j] = (f32x4){0.f, 0.f, 0.f, 0.f};

    const unsigned short* gA = g_agg + (size_t)m0 * DD;
    const unsigned short* gB = g_Wt + (size_t)n0 * DD;

    for (int k0 = 0; k0 < DD; k0 += BK) {
        // 24 chunks of 1 KB (A: 0..7, B: 8..23), 3 per wave; wave-uniform LDS
        // base, HW adds lane*16 -> linear [row][k].
#pragma unroll
        for (int i = 0; i < 3; ++i) {
            int c = wave * 3 + i;
            if (c < 8) {
                __builtin_amdgcn_global_load_lds(
                    (const __attribute__((address_space(1))) void*)
                        (gA + (size_t)(c * 16 + srow) * DD + k0 + skoff),
                    (__attribute__((address_space(3))) void*)(As + c * 512), 16, 0, 0);
            } else {
                __builtin_amdgcn_global_load_lds(
                    (const __attribute__((address_space(1))) void*)
                        (gB + (size_t)((c - 8) * 16 + srow) * DD + k0 + skoff),
                    (__attribute__((address_space(3))) void*)(Bs + (c - 8) * 512), 16, 0, 0);
            }
        }
        __syncthreads();   // compiler emits vmcnt(0) drain before s_barrier

        bf16x8 af[4], bf[4];
#pragma unroll
        for (int t = 0; t < 4; ++t) {
            af[t] = *(const bf16x8*)(&As[(wm * 64 + t * 16 + l16) * BK + quad * 8]);
            bf[t] = *(const bf16x8*)(&Bs[(wn * 64 + t * 16 + l16) * BK + quad * 8]);
        }
#pragma unroll
        for (int am = 0; am < 4; ++am)
#pragma unroll
            for (int bn = 0; bn < 4; ++bn)
                acc[am][bn] = __builtin_amdgcn_mfma_f32_16x16x32_bf16(
                    af[am], bf[bn], acc[am][bn], 0, 0, 0);
        __syncthreads();
    }

    // Epilogue: C/D layout col=l16, row=quad*4+r (m89/m91-verified).
    // NT stores: out is write-once, dense, full-line -> keep it out of L2.
#pragma unroll
    for (int am = 0; am < 4; ++am) {
        int row_base = m0 + wm * 64 + am * 16 + quad * 4;
#pragma unroll
        for (int bn = 0; bn < 4; ++bn) {
            int col = n0 + wn * 64 + bn * 16 + l16;
            float bv = bias[col];
#pragma unroll
            for (int rr = 0; rr < 4; ++rr) {
                int rowi = row_base + rr;
                if (rowi < NN)
                    __builtin_nontemporal_store(acc[am][bn][rr] + bv,
                                                out + (size_t)rowi * DD + col);
            }
        }
    }
}

extern "C" void kernel_launch(void* const* d_in, const int* in_sizes, int n_in,
                              void* d_out, int out_size, void* d_ws, size_t ws_size,
                              hipStream_t stream) {
    const float* x    = (const float*)d_in[0];
    const float* W    = (const float*)d_in[1];
    const float* bias = (const float*)d_in[2];
    const int*   src  = (const int*)d_in[3];
    const int*   dst  = (const int*)d_in[4];
    float* out = (float*)d_out;
    (void)d_ws; (void)ws_size;

    prep_all<<<FB_END, 256, 0, stream>>>(x, W, src, dst);        // fill || conv || Wt
    aggregate<<<(NN * 64 + 255) / 256, 256, 0, stream>>>();      // one wave/node
    gemm_kernel<<<NWG, 512, 0, stream>>>(out, bias);             // 782 blocks
}

// Round 13
// 402.982 us; speedup vs baseline: 1.5451x; 1.0182x over previous
//
#include <hip/hip_runtime.h>
#include <hip/hip_bf16.h>

#define NN 50000
#define NE 800000
#define DD 512
#define NPAD 50048   // 391 * 128, for 128-row GEMM tiles
#define STRIDE 64    // bucket-CSR slots; max deg ~35 for 800K->50K Poisson(16),
                     // P(deg>=64) ~ e^-40/node. Row = 256 B = 2 lines (was 3).

typedef __attribute__((ext_vector_type(8))) short bf16x8;
typedef __attribute__((ext_vector_type(4))) float f32x4;
typedef __attribute__((ext_vector_type(8))) unsigned short u16x8;

// R13 = R6 (best, 403.2) + STRIDE 96->64 (g_eidx 19.2->12.8 MB: less fill
// write-allocate thrash, less agg seg traffic). R12's NT epilogue reverted
// (+7 us: gemm FETCH was already ~32 MB — no eviction problem existed; NT
// loses L2 write-combining). Session NT verdict: scatter-NT -27, dense-NT -7,
// NT-loads-on-read-once-streams only safe use.
// Measured books: agg 131.5 (fabric wall; 3 structural attacks lost), gemm 54
// (dbuf/LDS-free/NT all lost), fill ~52 (R10 probe), ~140 us fixed harness
// dispatches. All remaining levers are noise-band or behind beaten walls.
__device__ __align__(16) unsigned short g_Wt[DD * DD];            // W^T bf16
__device__ __align__(16) unsigned short g_xb[(size_t)NN * DD];    // x in bf16 (51 MB)
__device__ __align__(16) unsigned short g_agg[(size_t)NPAD * DD]; // bf16 agg (A matrix)
__device__ unsigned g_cnt[NN];                                    // static zero-init
__device__ int g_eidx[(size_t)NN * STRIDE];                       // bucket CSR (12.8 MB)

// round-to-nearest-even fp32 -> bf16 (finite normal inputs)
static __device__ __forceinline__ unsigned short f2bf(float f) {
    unsigned u = __float_as_uint(f);
    u += 0x7fff + ((u >> 16) & 1);
    return (unsigned short)(u >> 16);
}
static __device__ __forceinline__ float bf2f(unsigned short u) {
    return __uint_as_float((unsigned)u << 16);
}

// Fused prep: fill (edge scatter) runs CONCURRENTLY with x->bf16 conv, W^T, pad-zero.
#define FB_FILL 3125                 // 800000 / 256 exactly
#define FB_CONV (FB_FILL + 12500)    // 50000*512/8/256
#define FB_WT   (FB_CONV + 1024)     // 512*512/256
#define FB_END  (FB_WT + 12)         // 48 pad rows * 512 / 8 / 256

__global__ void prep_all(const float* __restrict__ x, const float* __restrict__ W,
                         const int* __restrict__ src, const int* __restrict__ dst) {
    int b = blockIdx.x;
    int tid = threadIdx.x;
    if (b < FB_FILL) {
        int i = b * 256 + tid;                     // NE = 3125*256 exactly
        int d = dst[i];
        unsigned pos = atomicAdd(&g_cnt[d], 1u);
        if (pos < STRIDE) g_eidx[(size_t)d * STRIDE + pos] = src[i];
    } else if (b < FB_CONV) {
        size_t base = ((size_t)(b - FB_FILL) * 256 + tid) * 8;
        // x is read exactly once: nontemporal load, don't install 102 MB in L2
        f32x4 v0 = __builtin_nontemporal_load((const f32x4*)(x + base));
        f32x4 v1 = __builtin_nontemporal_load((const f32x4*)(x + base) + 1);
        u16x8 o;
        o[0] = f2bf(v0[0]); o[1] = f2bf(v0[1]); o[2] = f2bf(v0[2]); o[3] = f2bf(v0[3]);
        o[4] = f2bf(v1[0]); o[5] = f2bf(v1[1]); o[6] = f2bf(v1[2]); o[7] = f2bf(v1[3]);
        *(u16x8*)(g_xb + base) = o;                // normal store
    } else if (b < FB_WT) {
        int idx = (b - FB_CONV) * 256 + tid;       // coalesced read of W
        int k = idx >> 9, n = idx & 511;
        g_Wt[n * DD + k] = f2bf(W[idx]);           // g_Wt[n][k] = W[k][n]
    } else {
        int i = (b - FB_WT) * 256 + tid;           // 0..3071: zero 48 GEMM pad rows
        u16x8 z = {0, 0, 0, 0, 0, 0, 0, 0};
        *(u16x8*)(g_agg + (size_t)NN * DD + (size_t)i * 8) = z;
    }
}

// one wave per node: gather bf16 rows, fp32 register accumulation, bf16 write.
// Structurally done: 418 MB random-line fetch @ ~3.3 TB/s fabric wall.
__global__ void aggregate() {
    int v = (blockIdx.x * blockDim.x + threadIdx.x) >> 6;
    int lane = threadIdx.x & 63;
    if (v >= NN) return;
    int deg = (int)g_cnt[v];
    if (deg > STRIDE) deg = STRIDE;
    const int* seg = g_eidx + (size_t)v * STRIDE;
    float a[8] = {0.f, 0.f, 0.f, 0.f, 0.f, 0.f, 0.f, 0.f};
    int i = 0;
    for (; i + 3 < deg; i += 4) {  // 4 KB in flight per wave
        int s0 = seg[i], s1 = seg[i + 1], s2 = seg[i + 2], s3 = seg[i + 3];
        int4 q0 = *((const int4*)(g_xb + ((size_t)s0 << 9)) + lane);
        int4 q1 = *((const int4*)(g_xb + ((size_t)s1 << 9)) + lane);
        int4 q2 = *((const int4*)(g_xb + ((size_t)s2 << 9)) + lane);
        int4 q3 = *((const int4*)(g_xb + ((size_t)s3 << 9)) + lane);
        const unsigned short* u0 = (const unsigned short*)&q0;
        const unsigned short* u1 = (const unsigned short*)&q1;
        const unsigned short* u2 = (const unsigned short*)&q2;
        const unsigned short* u3 = (const unsigned short*)&q3;
#pragma unroll
        for (int j = 0; j < 8; ++j)
            a[j] += (bf2f(u0[j]) + bf2f(u1[j])) + (bf2f(u2[j]) + bf2f(u3[j]));
    }
    for (; i + 1 < deg; i += 2) {
        int s0 = seg[i], s1 = seg[i + 1];
        int4 q0 = *((const int4*)(g_xb + ((size_t)s0 << 9)) + lane);
        int4 q1 = *((const int4*)(g_xb + ((size_t)s1 << 9)) + lane);
        const unsigned short* u0 = (const unsigned short*)&q0;
        const unsigned short* u1 = (const unsigned short*)&q1;
#pragma unroll
        for (int j = 0; j < 8; ++j) a[j] += bf2f(u0[j]) + bf2f(u1[j]);
    }
    if (i < deg) {
        int s0 = seg[i];
        int4 q0 = *((const int4*)(g_xb + ((size_t)s0 << 9)) + lane);
        const unsigned short* u0 = (const unsigned short*)&q0;
#pragma unroll
        for (int j = 0; j < 8; ++j) a[j] += bf2f(u0[j]);
    }
    u16x8 o;
#pragma unroll
    for (int j = 0; j < 8; ++j) o[j] = f2bf(a[j]);
    *(u16x8*)(g_agg + ((size_t)v << 9) + lane * 8) = o;
}

// GEMM: m97 fragment structure, 128x256 tile, BK=32, 8 waves (2x4), 4x4 frags/wave.
// LDS staging is load-bearing (R11: LDS-free = 137 us, latency-bound at 30% occ).
// Plain epilogue stores (R12: NT-out was +7 us).
#define BM 128
#define BN 256
#define BK 32
#define NWG ((NPAD / BM) * (DD / BN))   // 391*2 = 782

__global__ __launch_bounds__(512) void gemm_kernel(float* __restrict__ out,
                                                   const float* __restrict__ bias) {
    __shared__ __align__(16) unsigned short As[BM * BK];   // 8 KB, [m][k] linear
    __shared__ __align__(16) unsigned short Bs[BN * BK];   // 16 KB, [n][k] linear

    // zero g_cnt for the NEXT graph replay (runs after aggregate's last read).
    {
        int gid = blockIdx.x * 512 + threadIdx.x;   // 782*512 >= NN
        if (gid < NN) g_cnt[gid] = 0;
    }

    // bijective XCD swizzle (m204 form; NWG = 782, r = 6)
    const int q = NWG >> 3, r = NWG & 7;
    int xcd = blockIdx.x & 7, sub = blockIdx.x >> 3;
    int swz = (xcd < r) ? xcd * (q + 1) + sub : r * (q + 1) + (xcd - r) * q + sub;
    const int m0 = (swz >> 1) * BM;
    const int n0 = (swz & 1) * BN;

    const int tid = threadIdx.x;
    const int wave = tid >> 6, lane = tid & 63;
    const int wm = wave >> 2, wn = wave & 3;       // 2x4 waves -> 64x64 quadrants
    const int quad = lane >> 4, l16 = lane & 15;

    const int srow = lane >> 2;          // staging: 0..15
    const int skoff = (lane & 3) * 8;    // shorts

    f32x4 acc[4][4];
#pragma unroll
    for (int i = 0; i < 4; ++i)
#pragma unroll
        for (int j = 0; j < 4; ++j) acc[i][j] = (f32x4){0.f, 0.f, 0.f, 0.f};

    const unsigned short* gA = g_agg + (size_t)m0 * DD;
    const unsigned short* gB = g_Wt + (size_t)n0 * DD;

    for (int k0 = 0; k0 < DD; k0 += BK) {
        // 24 chunks of 1 KB (A: 0..7, B: 8..23), 3 per wave; wave-uniform LDS
        // base, HW adds lane*16 -> linear [row][k].
#pragma unroll
        for (int i = 0; i < 3; ++i) {
            int c = wave * 3 + i;
            if (c < 8) {
                __builtin_amdgcn_global_load_lds(
                    (const __attribute__((address_space(1))) void*)
                        (gA + (size_t)(c * 16 + srow) * DD + k0 + skoff),
                    (__attribute__((address_space(3))) void*)(As + c * 512), 16, 0, 0);
            } else {
                __builtin_amdgcn_global_load_lds(
                    (const __attribute__((address_space(1))) void*)
                        (gB + (size_t)((c - 8) * 16 + srow) * DD + k0 + skoff),
                    (__attribute__((address_space(3))) void*)(Bs + (c - 8) * 512), 16, 0, 0);
            }
        }
        __syncthreads();   // compiler emits vmcnt(0) drain before s_barrier

        bf16x8 af[4], bf[4];
#pragma unroll
        for (int t = 0; t < 4; ++t) {
            af[t] = *(const bf16x8*)(&As[(wm * 64 + t * 16 + l16) * BK + quad * 8]);
            bf[t] = *(const bf16x8*)(&Bs[(wn * 64 + t * 16 + l16) * BK + quad * 8]);
        }
#pragma unroll
        for (int am = 0; am < 4; ++am)
#pragma unroll
            for (int bn = 0; bn < 4; ++bn)
                acc[am][bn] = __builtin_amdgcn_mfma_f32_16x16x32_bf16(
                    af[am], bf[bn], acc[am][bn], 0, 0, 0);
        __syncthreads();
    }

    // Epilogue: C/D layout col=l16, row=quad*4+r (m89/m91-verified).
#pragma unroll
    for (int am = 0; am < 4; ++am) {
        int row_base = m0 + wm * 64 + am * 16 + quad * 4;
#pragma unroll
        for (int bn = 0; bn < 4; ++bn) {
            int col = n0 + wn * 64 + bn * 16 + l16;
            float bv = bias[col];
#pragma unroll
            for (int rr = 0; rr < 4; ++rr) {
                int rowi = row_base + rr;
                if (rowi < NN) out[(size_t)rowi * DD + col] = acc[am][bn][rr] + bv;
            }
        }
    }
}

extern "C" void kernel_launch(void* const* d_in, const int* in_sizes, int n_in,
                              void* d_out, int out_size, void* d_ws, size_t ws_size,
                              hipStream_t stream) {
    const float* x    = (const float*)d_in[0];
    const float* W    = (const float*)d_in[1];
    const float* bias = (const float*)d_in[2];
    const int*   src  = (const int*)d_in[3];
    const int*   dst  = (const int*)d_in[4];
    float* out = (float*)d_out;
    (void)d_ws; (void)ws_size;

    prep_all<<<FB_END, 256, 0, stream>>>(x, W, src, dst);        // fill || conv || Wt
    aggregate<<<(NN * 64 + 255) / 256, 256, 0, stream>>>();      // one wave/node
    gemm_kernel<<<NWG, 512, 0, stream>>>(out, bias);             // 782 blocks
}